// Round 5
// baseline (359.502 us; speedup 1.0000x reference)
//
#include <hip/hip_runtime.h>
#include <math.h>

#define BN 4096
typedef unsigned short u16;
typedef unsigned int   u32;
typedef short bfx8 __attribute__((ext_vector_type(8)));
typedef float fx4  __attribute__((ext_vector_type(4)));

// ---- chunk tables: (base row in x, rows used) for the 31 masked means ----
__device__ const int c_base[31] = {
  276,
  211, 224, 237, 250, 263,
  662, 672, 682, 692, 702,
  612, 622, 632, 642, 652,
  397, 410, 423, 436, 449,
  512, 522, 532, 542, 552,
  862, 872, 882, 892, 902
};
__device__ const int c_rows[31] = {
  10,
  10,10,10,10,10,
  5,5,5,5,5,
  5,5,5,5,5,
  10,10,10,10,10,
  5,5,5,5,5,
  5,5,5,5,5
};

__device__ __forceinline__ u16 f2bf(float f){
  u32 u = __float_as_uint(f);
  return (u16)((u + 0x7FFFu + ((u >> 16) & 1u)) >> 16);   // RNE
}
__device__ __forceinline__ float bf2f(u16 h){ return __uint_as_float(((u32)h) << 16); }
__device__ __forceinline__ float4 ld4(const float* p){ return *(const float4*)p; }
__device__ __forceinline__ float frcp(float x){ return __builtin_amdgcn_rcpf(x); }
__device__ __forceinline__ float sigf(float v){ return frcp(1.f + __expf(-v)); }
__device__ __forceinline__ float tanhf_(float v){ return 1.f - 2.f*frcp(1.f + __expf(2.f*v)); }

// ---- Kernel 1: count (blocks 0..247) + table->bf16 conversion (15625 blocks)
//      + weight prep (757 blocks). All independent work, one dispatch. ----
extern "C" __global__ __launch_bounds__(256)
void setup_kernel(const float* __restrict__ x, int* __restrict__ cnt8,
                  const float* __restrict__ we, u16* __restrict__ we16,
                  const float* __restrict__ Wih, const float* __restrict__ Whh,
                  const float* __restrict__ wl,  const float* __restrict__ bih,
                  const float* __restrict__ bhh,
                  const float* __restrict__ cqw, const float* __restrict__ cquw,
                  const float* __restrict__ ww,  const float* __restrict__ l1w,
                  const float* __restrict__ l2w,
                  u16* __restrict__ Wcb, u16* __restrict__ wlb,
                  float* __restrict__ bias_sum,
                  float* __restrict__ cqwT, float* __restrict__ cquwT,
                  float* __restrict__ wwT,  float* __restrict__ lwT){
  const int blk = blockIdx.x;
  if (blk < 248){
    __shared__ int red[256];
    const int c = blk >> 3, part = blk & 7;
    const int base = c_base[c], rows = c_rows[c];
    const int n_per = rows * 512;
    const int start = part * n_per;
    int s = 0;
    for (int i = start + threadIdx.x; i < start + n_per; i += 256){
      float v = x[(size_t)(base + (i >> 12)) * BN + (i & 4095)];
      s += (v > 0.f) ? 1 : ((v < 0.f) ? -1 : 0);
    }
    red[threadIdx.x] = s; __syncthreads();
    for (int off = 128; off > 0; off >>= 1){
      if (threadIdx.x < off) red[threadIdx.x] += red[threadIdx.x + off];
      __syncthreads();
    }
    if (threadIdx.x == 0) cnt8[blk] = red[0];
    return;
  }
  if (blk < 248 + 15625){
    // table conversion: 32,000,000 elems, 8 per thread
    size_t e0 = (size_t)(blk - 248) * 2048 + (size_t)threadIdx.x * 8;
    float4 v0 = ld4(we + e0);
    float4 v1 = ld4(we + e0 + 4);
    u32 p[4];
    p[0] = (u32)f2bf(v0.x) | ((u32)f2bf(v0.y) << 16);
    p[1] = (u32)f2bf(v0.z) | ((u32)f2bf(v0.w) << 16);
    p[2] = (u32)f2bf(v1.x) | ((u32)f2bf(v1.y) << 16);
    p[3] = (u32)f2bf(v1.z) | ((u32)f2bf(v1.w) << 16);
    *(uint4*)(we16 + e0) = *(uint4*)p;
    return;
  }
  int idx = (blk - 248 - 15625) * 256 + threadIdx.x;
  if (idx < 131072){
    int s = idx >> 15, rem = idx & 32767, n = rem >> 7, k = rem & 127;
    float v = (k < 64) ? Wih[s*16384 + n*64 + k] : Whh[s*16384 + n*64 + (k-64)];
    Wcb[idx] = f2bf(v);
  } else if (idx < 147456){
    int j = idx - 131072;
    wlb[j] = f2bf(wl[j]);
  } else if (idx < 148480){
    int j = idx - 147456;
    bias_sum[j] = bih[j] + bhh[j];
  } else if (idx < 177152){
    int j = idx - 148480;                    // cqwT[448][64]
    int k = j >> 6, m = j & 63;
    cqwT[j] = cqw[m*448 + k];
  } else if (idx < 185344){
    int j = idx - 177152;                    // cquwT[128][64]
    int k = j >> 6, m = j & 63;
    cquwT[j] = cquw[m*128 + k];
  } else if (idx < 190528){
    int j = idx - 185344;                    // wwT[81][64]
    int k = j >> 6, m = j & 63;
    wwT[j] = ww[m*81 + k];
  } else if (idx < 193600){
    int j = idx - 190528;                    // lwT[2][24][64]
    int cs = j >= 1536;
    int r = j - (cs ? 1536 : 0);
    int k = r >> 6, m = r & 63;
    lwT[j] = (cs ? l2w : l1w)[m*24 + k];
  }
}

// ---- Kernel 2: means, gathering from the bf16 table (half traffic, L3-resident) ----
template<int ROWS>
__device__ __forceinline__ void means_body8(const float* __restrict__ x,
                                            const u16* __restrict__ we16,
                                            float L, int base, int b0, int lane,
                                            float* m){
  float a[8];
  #pragma unroll
  for (int j = 0; j < 8; ++j) a[j] = 0.f;
  #pragma unroll
  for (int r = 0; r < ROWS; ++r){
    float4 i0 = ld4(x + (size_t)(base + r) * BN + b0);
    float4 i1 = ld4(x + (size_t)(base + r) * BN + b0 + 4);
    float wr = ((float)r < L) ? 1.f : 0.f;
    a[0] += wr * bf2f(we16[(size_t)(int)i0.x * 64 + lane]);
    a[1] += wr * bf2f(we16[(size_t)(int)i0.y * 64 + lane]);
    a[2] += wr * bf2f(we16[(size_t)(int)i0.z * 64 + lane]);
    a[3] += wr * bf2f(we16[(size_t)(int)i0.w * 64 + lane]);
    a[4] += wr * bf2f(we16[(size_t)(int)i1.x * 64 + lane]);
    a[5] += wr * bf2f(we16[(size_t)(int)i1.y * 64 + lane]);
    a[6] += wr * bf2f(we16[(size_t)(int)i1.z * 64 + lane]);
    a[7] += wr * bf2f(we16[(size_t)(int)i1.w * 64 + lane]);
  }
  float rL = 1.f / L;
  #pragma unroll
  for (int j = 0; j < 8; ++j) m[j] = a[j] * rL;
}

extern "C" __global__ __launch_bounds__(256)
void means_kernel(const float* __restrict__ x, const u16* __restrict__ we16,
                  const int* __restrict__ cnt8, u16* __restrict__ Mbf){
  const int c = blockIdx.x >> 7, tile = blockIdx.x & 127;
  const int w = threadIdx.x >> 6, lane = threadIdx.x & 63;
  const int b0 = tile * 32 + w * 8;
  const int base = c_base[c], rows = c_rows[c];
  int n = 0;
  #pragma unroll
  for (int p = 0; p < 8; ++p) n += cnt8[c*8 + p];
  const float L = fminf(fmaxf((float)n, 1.f), (float)rows);
  float m[8];
  if (rows == 5) means_body8<5>(x, we16, L, base, b0, lane, m);
  else          means_body8<10>(x, we16, L, base, b0, lane, m);
  #pragma unroll
  for (int j = 0; j < 8; ++j)
    Mbf[((size_t)c * BN + b0 + j) * 64 + lane] = f2bf(m[j]);
}

// ---- Kernel 3: LSTM streams via bf16 MFMA ----
extern "C" __global__ __launch_bounds__(256, 1)
void lstm_kernel(const u16* __restrict__ Wcb, const u16* __restrict__ wlb,
                 const float* __restrict__ bias_sum, const u16* __restrict__ Mbf,
                 const float* __restrict__ h0, const float* __restrict__ c0,
                 const float* __restrict__ bl, float* __restrict__ S){
  __shared__ u16 Xh[64][136];

  const int tid = threadIdx.x, w = tid >> 6, lane = tid & 63;
  const int quad = lane >> 4, l0 = lane & 15;
  const int st = blockIdx.x & 3, tile = blockIdx.x >> 2, b0 = tile * 64;
  const int brow = 16 * w + l0;
  const u16* Wc = Wcb + (size_t)st * 32768;

  fx4 bias4[16];
  #pragma unroll
  for (int mt = 0; mt < 16; ++mt)
    bias4[mt] = *(const fx4*)(bias_sum + st*256 + mt*16 + quad*4);

  float cst[4][4];
  #pragma unroll
  for (int dc = 0; dc < 4; ++dc){
    float4 v = ld4(c0 + ((size_t)st*BN + b0 + brow)*64 + dc*16 + quad*4);
    cst[dc][0]=v.x; cst[dc][1]=v.y; cst[dc][2]=v.z; cst[dc][3]=v.w;
  }
  {
    const float* hp = h0 + ((size_t)st*BN + b0 + brow)*64 + quad*16;
    #pragma unroll
    for (int i = 0; i < 4; ++i){
      float4 v = ld4(hp + i*4);
      u32* dst = (u32*)&Xh[brow][64 + quad*16 + i*4];
      dst[0] = (u32)f2bf(v.x) | ((u32)f2bf(v.y) << 16);
      dst[1] = (u32)f2bf(v.z) | ((u32)f2bf(v.w) << 16);
    }
  }

  for (int t = 0; t < 5; ++t){
    {
      const u16* src = Mbf + ((size_t)(1 + st*5 + t)*BN + b0 + brow)*64 + quad*16;
      *(uint4*)&Xh[brow][quad*16]     = *(const uint4*)src;
      *(uint4*)&Xh[brow][quad*16 + 8] = *(const uint4*)(src + 8);
    }
    __syncthreads();

    fx4 acc[16];
    #pragma unroll
    for (int mt = 0; mt < 16; ++mt) acc[mt] = bias4[mt];
    #pragma unroll
    for (int kc = 0; kc < 4; ++kc){
      bfx8 bfr = *(const bfx8*)&Xh[brow][kc*32 + quad*8];
      #pragma unroll
      for (int mt = 0; mt < 16; ++mt){
        bfx8 afr = *(const bfx8*)(Wc + (size_t)(mt*16 + l0)*128 + kc*32 + quad*8);
        acc[mt] = __builtin_amdgcn_mfma_f32_16x16x32_bf16(afr, bfr, acc[mt], 0, 0, 0);
      }
    }
    #pragma unroll
    for (int dc = 0; dc < 4; ++dc){
      u16 hv[4];
      #pragma unroll
      for (int r = 0; r < 4; ++r){
        float ig = sigf(acc[dc][r]);
        float fg = sigf(acc[4 + dc][r]);
        float gg = tanhf_(acc[8 + dc][r]);
        float og = sigf(acc[12 + dc][r]);
        float cc = fg * cst[dc][r] + ig * gg;
        cst[dc][r] = cc;
        hv[r] = f2bf(og * tanhf_(cc));
      }
      u32* dst = (u32*)&Xh[brow][64 + dc*16 + quad*4];
      dst[0] = (u32)hv[0] | ((u32)hv[1] << 16);
      dst[1] = (u32)hv[2] | ((u32)hv[3] << 16);
    }
    __syncthreads();
  }

  fx4 acc2[4];
  #pragma unroll
  for (int mt = 0; mt < 4; ++mt){ acc2[mt].x=0.f; acc2[mt].y=0.f; acc2[mt].z=0.f; acc2[mt].w=0.f; }
  #pragma unroll
  for (int kc = 0; kc < 2; ++kc){
    bfx8 bfr = *(const bfx8*)&Xh[brow][64 + kc*32 + quad*8];
    #pragma unroll
    for (int mt = 0; mt < 4; ++mt){
      bfx8 afr = *(const bfx8*)(wlb + (size_t)st*4096 + (size_t)(mt*16 + l0)*64 + kc*32 + quad*8);
      acc2[mt] = __builtin_amdgcn_mfma_f32_16x16x32_bf16(afr, bfr, acc2[mt], 0, 0, 0);
    }
  }
  #pragma unroll
  for (int mt = 0; mt < 4; ++mt){
    fx4 blv = *(const fx4*)(bl + st*64 + mt*16 + quad*4);
    fx4 o;
    o.x = tanhf_(acc2[mt].x + blv.x);
    o.y = tanhf_(acc2[mt].y + blv.y);
    o.z = tanhf_(acc2[mt].z + blv.z);
    o.w = tanhf_(acc2[mt].w + blv.w);
    *(fx4*)(S + ((size_t)st*BN + b0 + brow)*64 + mt*16 + quad*4) = o;
  }
}

// ---- Kernel 4: tail. Block = 8 batch, thread = (b = tid&7, mg = tid>>3). ----
extern "C" __global__ __launch_bounds__(256)
void final_kernel(
    const float* __restrict__ x,   const u16* __restrict__ Mbf,
    const float* __restrict__ S,
    const float* __restrict__ c1w, const float* __restrict__ c1b,
    const float* __restrict__ c2w, const float* __restrict__ c2b,
    const float* __restrict__ l1b, const float* __restrict__ l2b,
    const float* __restrict__ wwT, const float* __restrict__ wb,
    const float* __restrict__ cqwT,const float* __restrict__ cqb,
    const float* __restrict__ cquwT,const float* __restrict__ cqub,
    const float* __restrict__ lwT, const float* __restrict__ dww,
    const float* __restrict__ dwb, float* __restrict__ out)
{
  __shared__ float cb[448][9];
  __shared__ float qwin[128][9];
  __shared__ float sm[5][64][9];
  __shared__ float co[48][9];
  __shared__ float cwS[12][130];
  __shared__ float red[32][8];

  const int tid = threadIdx.x;
  const int b   = tid & 7;
  const int mg  = tid >> 3;
  const int b0  = blockIdx.x * 8;

  {
    const int e = tid & 63, rr = tid >> 6;
    #pragma unroll
    for (int i = 0; i < 2; ++i){
      const int bb = rr*2 + i;
      cb[e][bb] = bf2f(Mbf[(size_t)(b0 + bb)*64 + e]);
      #pragma unroll
      for (int s = 0; s < 4; ++s)
        cb[64 + s*64 + e][bb] = S[((size_t)s*BN + b0 + bb)*64 + e];
    }
  }

  {
    float a0 = wb[mg*2], a1 = wb[mg*2+1];
    #pragma unroll 4
    for (int k = 0; k < 81; ++k){
      float xv = x[(size_t)k*BN + b0 + b];
      float2 wv = *(const float2*)(wwT + k*64 + mg*2);
      a0 += wv.x * xv; a1 += wv.y * xv;
    }
    qwin[64 + mg*2][b]     = tanhf_(a0);
    qwin[64 + mg*2 + 1][b] = tanhf_(a1);
  }

  for (int cs = 0; cs < 2; ++cs){
    const float* cw    = cs ? c2w : c1w;
    const float* cbias = cs ? c2b : c1b;
    const float* lb    = cs ? l2b : l1b;

    __syncthreads();
    {
      const int e = tid & 63, rr = tid >> 6;
      #pragma unroll
      for (int t = 0; t < 5; ++t)
        #pragma unroll
        for (int i = 0; i < 2; ++i){
          const int bb = rr*2 + i;
          sm[t][e][bb] = bf2f(Mbf[((size_t)(21 + cs*5 + t)*BN + b0 + bb)*64 + e]);
        }
      for (int r2 = tid; r2 < 1536; r2 += 256){
        const int o = r2 >> 7, j = r2 & 127;
        cwS[o][j] = cw[o*128 + j];
      }
    }
    __syncthreads();

    if (mg < 24){
      const int o = mg >> 1, hb = (mg & 1) * 2;
      float a0 = cbias[o], a1 = cbias[o];
      #pragma unroll 4
      for (int e = 0; e < 64; ++e){
        float w0 = cwS[o][e], w1 = cwS[o][64 + e];
        float s0 = sm[hb][e][b], s1 = sm[hb+1][e][b], s2 = sm[hb+2][e][b];
        a0 += w0*s0 + w1*s1;
        a1 += w0*s1 + w1*s2;
      }
      co[o*4 + hb][b]     = fmaxf(a0, 0.f);
      co[o*4 + hb + 1][b] = fmaxf(a1, 0.f);
    }
    __syncthreads();

    {
      float a0 = lb[mg*2], a1 = lb[mg*2+1];
      #pragma unroll
      for (int k = 0; k < 24; ++k){
        const int p = k >= 12, o = k - (p ? 12 : 0);
        float f = fmaxf(co[o*4 + 2*p][b], co[o*4 + 2*p + 1][b]);
        float2 lv = *(const float2*)(lwT + (cs*24 + k)*64 + mg*2);
        a0 += lv.x * f; a1 += lv.y * f;
      }
      cb[320 + cs*64 + mg*2][b]     = fmaxf(a0, 0.f);
      cb[320 + cs*64 + mg*2 + 1][b] = fmaxf(a1, 0.f);
    }
  }

  __syncthreads();
  {
    float a0 = cqb[mg*2], a1 = cqb[mg*2+1];
    #pragma unroll 8
    for (int k = 0; k < 448; ++k){
      float a = cb[k][b];
      float2 wv = *(const float2*)(cqwT + k*64 + mg*2);
      a0 += wv.x * a; a1 += wv.y * a;
    }
    qwin[mg*2][b]     = tanhf_(a0);
    qwin[mg*2 + 1][b] = tanhf_(a1);
  }
  __syncthreads();
  {
    float a0 = cqub[mg*2], a1 = cqub[mg*2+1];
    #pragma unroll 8
    for (int k = 0; k < 128; ++k){
      float a = qwin[k][b];
      float2 wv = *(const float2*)(cquwT + k*64 + mg*2);
      a0 += wv.x * a; a1 += wv.y * a;
    }
    float2 dv = *(const float2*)(dww + mg*2);
    red[mg][b] = dv.x * tanhf_(a0) + dv.y * tanhf_(a1);
  }
  __syncthreads();
  if (tid < 8){
    float s = dwb[0];
    #pragma unroll 8
    for (int g = 0; g < 32; ++g) s += red[g][tid];
    out[b0 + tid] = s;
  }
}

extern "C" void kernel_launch(void* const* d_in, const int* in_sizes, int n_in,
                              void* d_out, int out_size, void* d_ws, size_t ws_size,
                              hipStream_t stream) {
  const float* x    = (const float*)d_in[0];
  const float* we   = (const float*)d_in[1];
  const float* Wih  = (const float*)d_in[2];
  const float* Whh  = (const float*)d_in[3];
  const float* bihp = (const float*)d_in[4];
  const float* bhhp = (const float*)d_in[5];
  const float* h0   = (const float*)d_in[6];
  const float* c0   = (const float*)d_in[7];
  const float* wl   = (const float*)d_in[8];
  const float* bl   = (const float*)d_in[9];
  const float* c1w  = (const float*)d_in[10];
  const float* c1b  = (const float*)d_in[11];
  const float* l1w  = (const float*)d_in[12];
  const float* l1b  = (const float*)d_in[13];
  const float* c2w  = (const float*)d_in[14];
  const float* c2b  = (const float*)d_in[15];
  const float* l2w  = (const float*)d_in[16];
  const float* l2b  = (const float*)d_in[17];
  const float* ww   = (const float*)d_in[18];
  const float* wb   = (const float*)d_in[19];
  const float* cqw  = (const float*)d_in[20];
  const float* cqb  = (const float*)d_in[21];
  const float* cquw = (const float*)d_in[22];
  const float* cqub = (const float*)d_in[23];
  const float* dww  = (const float*)d_in[24];
  const float* dwb  = (const float*)d_in[25];

  char* ws = (char*)d_ws;
  int*   cnt8  = (int*)ws;                      // 992 B (pad 1024)
  u16*   Mbf   = (u16*)(ws + 1024);             // 16,252,928
  u16*   Wcb   = (u16*)(ws + 16253952);         // 262,144
  u16*   wlb   = (u16*)(ws + 16516096);         // 32,768
  float* bias  = (float*)(ws + 16548864);       // 4,096
  float* S     = (float*)(ws + 16552960);       // 4,194,304
  float* cqwT  = (float*)(ws + 20747264);       // 114,688
  float* cquwT = (float*)(ws + 20861952);       // 32,768
  float* wwT   = (float*)(ws + 20894720);       // 20,736
  float* lwT   = (float*)(ws + 20915456);       // 12,288
  u16*   we16  = (u16*)(ws + 20927744);         // 64,000,000 (end 84,927,744)

  setup_kernel<<<16630, 256, 0, stream>>>(x, cnt8, we, we16,
      Wih, Whh, wl, bihp, bhhp, cqw, cquw, ww, l1w, l2w,
      Wcb, wlb, bias, cqwT, cquwT, wwT, lwT);
  means_kernel<<<3968, 256, 0, stream>>>(x, we16, cnt8, Mbf);
  lstm_kernel<<<256, 256, 0, stream>>>(Wcb, wlb, bias, Mbf, h0, c0, bl, S);
  final_kernel<<<512, 256, 0, stream>>>(x, Mbf, S,
      c1w, c1b, c2w, c2b, l1b, l2b,
      wwT, wb, cqwT, cqb, cquwT, cqub, lwT, dww, dwb, (float*)d_out);
}

// Round 6
// 348.020 us; speedup vs baseline: 1.0330x; 1.0330x over previous
//
#include <hip/hip_runtime.h>
#include <math.h>

#define BN 4096
typedef unsigned short u16;
typedef unsigned int   u32;
typedef short bfx8 __attribute__((ext_vector_type(8)));
typedef float fx4  __attribute__((ext_vector_type(4)));

// ---- chunk tables: (base row in x, rows used) for the 31 masked means ----
__device__ const int c_base[31] = {
  276,
  211, 224, 237, 250, 263,
  662, 672, 682, 692, 702,
  612, 622, 632, 642, 652,
  397, 410, 423, 436, 449,
  512, 522, 532, 542, 552,
  862, 872, 882, 892, 902
};
__device__ const int c_rows[31] = {
  10,
  10,10,10,10,10,
  5,5,5,5,5,
  5,5,5,5,5,
  10,10,10,10,10,
  5,5,5,5,5,
  5,5,5,5,5
};

__device__ __forceinline__ u16 f2bf(float f){
  u32 u = __float_as_uint(f);
  return (u16)((u + 0x7FFFu + ((u >> 16) & 1u)) >> 16);   // RNE
}
__device__ __forceinline__ float bf2f(u16 h){ return __uint_as_float(((u32)h) << 16); }
__device__ __forceinline__ float4 ld4(const float* p){ return *(const float4*)p; }
__device__ __forceinline__ float frcp(float x){ return __builtin_amdgcn_rcpf(x); }
__device__ __forceinline__ float sigf(float v){ return frcp(1.f + __expf(-v)); }
__device__ __forceinline__ float tanhf_(float v){ return 1.f - 2.f*frcp(1.f + __expf(2.f*v)); }

// ---- Kernel 1: sign-count partials. Block (c,part) writes its own slot. ----
extern "C" __global__ __launch_bounds__(256)
void count_kernel(const float* __restrict__ x, int* __restrict__ cnt8){
  __shared__ int red[256];
  const int c = blockIdx.x >> 3, part = blockIdx.x & 7;
  const int base = c_base[c], rows = c_rows[c];
  const int n_per = rows * 512;
  const int start = part * n_per;
  int s = 0;
  for (int i = start + threadIdx.x; i < start + n_per; i += 256){
    float v = x[(size_t)(base + (i >> 12)) * BN + (i & 4095)];
    s += (v > 0.f) ? 1 : ((v < 0.f) ? -1 : 0);
  }
  red[threadIdx.x] = s; __syncthreads();
  for (int off = 128; off > 0; off >>= 1){
    if (threadIdx.x < off) red[threadIdx.x] += red[threadIdx.x + off];
    __syncthreads();
  }
  if (threadIdx.x == 0) cnt8[blockIdx.x] = red[0];
}

// ---- Kernel 2: means (blocks 0..1983, 16 batch/wave) + weight prep (rest) ----
// Gathers use non-temporal loads (bypass L2 allocation: 128MB table can't reuse L2
// anyway; keep L2 for x / Mbf / weights). 16 independent gathers in flight per row.
template<int ROWS>
__device__ __forceinline__ void means_body16(const float* __restrict__ x,
                                             const float* __restrict__ we,
                                             float L, int base, int b0, int lane,
                                             float* m){
  float a[16];
  #pragma unroll
  for (int j = 0; j < 16; ++j) a[j] = 0.f;
  for (int r = 0; r < ROWS; ++r){
    float4 iv[4];
    #pragma unroll
    for (int q = 0; q < 4; ++q)
      iv[q] = ld4(x + (size_t)(base + r) * BN + b0 + q*4);
    float wr = ((float)r < L) ? 1.f : 0.f;
    const float* idxf = (const float*)iv;
    #pragma unroll
    for (int j = 0; j < 16; ++j){
      float v = __builtin_nontemporal_load(we + (size_t)(int)idxf[j] * 64 + lane);
      a[j] += wr * v;
    }
  }
  float rL = 1.f / L;
  #pragma unroll
  for (int j = 0; j < 16; ++j) m[j] = a[j] * rL;
}

extern "C" __global__ __launch_bounds__(256)
void meansprep_kernel(const float* __restrict__ x, const float* __restrict__ we,
                      const int* __restrict__ cnt8, u16* __restrict__ Mbf,
                      const float* __restrict__ Wih, const float* __restrict__ Whh,
                      const float* __restrict__ wl,  const float* __restrict__ bih,
                      const float* __restrict__ bhh,
                      const float* __restrict__ cqw, const float* __restrict__ cquw,
                      const float* __restrict__ ww,  const float* __restrict__ l1w,
                      const float* __restrict__ l2w,
                      u16* __restrict__ Wcb, u16* __restrict__ wlb,
                      float* __restrict__ bias_sum,
                      float* __restrict__ cqwT, float* __restrict__ cquwT,
                      float* __restrict__ wwT,  float* __restrict__ lwT){
  const int blk = blockIdx.x;
  if (blk < 1984){
    const int c = blk >> 6, tile = blk & 63;
    const int w = threadIdx.x >> 6, lane = threadIdx.x & 63;
    const int b0 = tile * 64 + w * 16;
    const int base = c_base[c], rows = c_rows[c];
    int n = 0;
    #pragma unroll
    for (int p = 0; p < 8; ++p) n += cnt8[c*8 + p];
    const float L = fminf(fmaxf((float)n, 1.f), (float)rows);
    float m[16];
    if (rows == 5) means_body16<5>(x, we, L, base, b0, lane, m);
    else          means_body16<10>(x, we, L, base, b0, lane, m);
    #pragma unroll
    for (int j = 0; j < 16; ++j)
      Mbf[((size_t)c * BN + b0 + j) * 64 + lane] = f2bf(m[j]);
    return;
  }
  int idx = (blk - 1984) * 256 + threadIdx.x;
  if (idx < 131072){
    int s = idx >> 15, rem = idx & 32767, n = rem >> 7, k = rem & 127;
    float v = (k < 64) ? Wih[s*16384 + n*64 + k] : Whh[s*16384 + n*64 + (k-64)];
    Wcb[idx] = f2bf(v);
  } else if (idx < 147456){
    int j = idx - 131072;
    wlb[j] = f2bf(wl[j]);
  } else if (idx < 148480){
    int j = idx - 147456;
    bias_sum[j] = bih[j] + bhh[j];
  } else if (idx < 177152){
    int j = idx - 148480;                    // cqwT[448][64]
    int k = j >> 6, m = j & 63;
    cqwT[j] = cqw[m*448 + k];
  } else if (idx < 185344){
    int j = idx - 177152;                    // cquwT[128][64]
    int k = j >> 6, m = j & 63;
    cquwT[j] = cquw[m*128 + k];
  } else if (idx < 190528){
    int j = idx - 185344;                    // wwT[81][64]
    int k = j >> 6, m = j & 63;
    wwT[j] = ww[m*81 + k];
  } else if (idx < 193600){
    int j = idx - 190528;                    // lwT[2][24][64]
    int cs = j >= 1536;
    int r = j - (cs ? 1536 : 0);
    int k = r >> 6, m = r & 63;
    lwT[j] = (cs ? l2w : l1w)[m*24 + k];
  }
}

// ---- Kernel 3: LSTM streams via bf16 MFMA ----
extern "C" __global__ __launch_bounds__(256, 1)
void lstm_kernel(const u16* __restrict__ Wcb, const u16* __restrict__ wlb,
                 const float* __restrict__ bias_sum, const u16* __restrict__ Mbf,
                 const float* __restrict__ h0, const float* __restrict__ c0,
                 const float* __restrict__ bl, float* __restrict__ S){
  __shared__ u16 Xh[64][136];

  const int tid = threadIdx.x, w = tid >> 6, lane = tid & 63;
  const int quad = lane >> 4, l0 = lane & 15;
  const int st = blockIdx.x & 3, tile = blockIdx.x >> 2, b0 = tile * 64;
  const int brow = 16 * w + l0;
  const u16* Wc = Wcb + (size_t)st * 32768;

  fx4 bias4[16];
  #pragma unroll
  for (int mt = 0; mt < 16; ++mt)
    bias4[mt] = *(const fx4*)(bias_sum + st*256 + mt*16 + quad*4);

  float cst[4][4];
  #pragma unroll
  for (int dc = 0; dc < 4; ++dc){
    float4 v = ld4(c0 + ((size_t)st*BN + b0 + brow)*64 + dc*16 + quad*4);
    cst[dc][0]=v.x; cst[dc][1]=v.y; cst[dc][2]=v.z; cst[dc][3]=v.w;
  }
  {
    const float* hp = h0 + ((size_t)st*BN + b0 + brow)*64 + quad*16;
    #pragma unroll
    for (int i = 0; i < 4; ++i){
      float4 v = ld4(hp + i*4);
      u32* dst = (u32*)&Xh[brow][64 + quad*16 + i*4];
      dst[0] = (u32)f2bf(v.x) | ((u32)f2bf(v.y) << 16);
      dst[1] = (u32)f2bf(v.z) | ((u32)f2bf(v.w) << 16);
    }
  }

  for (int t = 0; t < 5; ++t){
    {
      const u16* src = Mbf + ((size_t)(1 + st*5 + t)*BN + b0 + brow)*64 + quad*16;
      *(uint4*)&Xh[brow][quad*16]     = *(const uint4*)src;
      *(uint4*)&Xh[brow][quad*16 + 8] = *(const uint4*)(src + 8);
    }
    __syncthreads();

    fx4 acc[16];
    #pragma unroll
    for (int mt = 0; mt < 16; ++mt) acc[mt] = bias4[mt];
    #pragma unroll
    for (int kc = 0; kc < 4; ++kc){
      bfx8 bfr = *(const bfx8*)&Xh[brow][kc*32 + quad*8];
      #pragma unroll
      for (int mt = 0; mt < 16; ++mt){
        bfx8 afr = *(const bfx8*)(Wc + (size_t)(mt*16 + l0)*128 + kc*32 + quad*8);
        acc[mt] = __builtin_amdgcn_mfma_f32_16x16x32_bf16(afr, bfr, acc[mt], 0, 0, 0);
      }
    }
    #pragma unroll
    for (int dc = 0; dc < 4; ++dc){
      u16 hv[4];
      #pragma unroll
      for (int r = 0; r < 4; ++r){
        float ig = sigf(acc[dc][r]);
        float fg = sigf(acc[4 + dc][r]);
        float gg = tanhf_(acc[8 + dc][r]);
        float og = sigf(acc[12 + dc][r]);
        float cc = fg * cst[dc][r] + ig * gg;
        cst[dc][r] = cc;
        hv[r] = f2bf(og * tanhf_(cc));
      }
      u32* dst = (u32*)&Xh[brow][64 + dc*16 + quad*4];
      dst[0] = (u32)hv[0] | ((u32)hv[1] << 16);
      dst[1] = (u32)hv[2] | ((u32)hv[3] << 16);
    }
    __syncthreads();
  }

  fx4 acc2[4];
  #pragma unroll
  for (int mt = 0; mt < 4; ++mt){ acc2[mt].x=0.f; acc2[mt].y=0.f; acc2[mt].z=0.f; acc2[mt].w=0.f; }
  #pragma unroll
  for (int kc = 0; kc < 2; ++kc){
    bfx8 bfr = *(const bfx8*)&Xh[brow][64 + kc*32 + quad*8];
    #pragma unroll
    for (int mt = 0; mt < 4; ++mt){
      bfx8 afr = *(const bfx8*)(wlb + (size_t)st*4096 + (size_t)(mt*16 + l0)*64 + kc*32 + quad*8);
      acc2[mt] = __builtin_amdgcn_mfma_f32_16x16x32_bf16(afr, bfr, acc2[mt], 0, 0, 0);
    }
  }
  #pragma unroll
  for (int mt = 0; mt < 4; ++mt){
    fx4 blv = *(const fx4*)(bl + st*64 + mt*16 + quad*4);
    fx4 o;
    o.x = tanhf_(acc2[mt].x + blv.x);
    o.y = tanhf_(acc2[mt].y + blv.y);
    o.z = tanhf_(acc2[mt].z + blv.z);
    o.w = tanhf_(acc2[mt].w + blv.w);
    *(fx4*)(S + ((size_t)st*BN + b0 + brow)*64 + mt*16 + quad*4) = o;
  }
}

// ---- Kernel 4: tail. Block = 8 batch, thread = (b = tid&7, mg = tid>>3). ----
extern "C" __global__ __launch_bounds__(256)
void final_kernel(
    const float* __restrict__ x,   const u16* __restrict__ Mbf,
    const float* __restrict__ S,
    const float* __restrict__ c1w, const float* __restrict__ c1b,
    const float* __restrict__ c2w, const float* __restrict__ c2b,
    const float* __restrict__ l1b, const float* __restrict__ l2b,
    const float* __restrict__ wwT, const float* __restrict__ wb,
    const float* __restrict__ cqwT,const float* __restrict__ cqb,
    const float* __restrict__ cquwT,const float* __restrict__ cqub,
    const float* __restrict__ lwT, const float* __restrict__ dww,
    const float* __restrict__ dwb, float* __restrict__ out)
{
  __shared__ float cb[448][9];
  __shared__ float qwin[128][9];
  __shared__ float sm[5][64][9];
  __shared__ float co[48][9];
  __shared__ float cwS[12][130];
  __shared__ float red[32][8];

  const int tid = threadIdx.x;
  const int b   = tid & 7;
  const int mg  = tid >> 3;
  const int b0  = blockIdx.x * 8;

  {
    const int e = tid & 63, rr = tid >> 6;
    #pragma unroll
    for (int i = 0; i < 2; ++i){
      const int bb = rr*2 + i;
      cb[e][bb] = bf2f(Mbf[(size_t)(b0 + bb)*64 + e]);
      #pragma unroll
      for (int s = 0; s < 4; ++s)
        cb[64 + s*64 + e][bb] = S[((size_t)s*BN + b0 + bb)*64 + e];
    }
  }

  {
    float a0 = wb[mg*2], a1 = wb[mg*2+1];
    #pragma unroll 4
    for (int k = 0; k < 81; ++k){
      float xv = x[(size_t)k*BN + b0 + b];
      float2 wv = *(const float2*)(wwT + k*64 + mg*2);
      a0 += wv.x * xv; a1 += wv.y * xv;
    }
    qwin[64 + mg*2][b]     = tanhf_(a0);
    qwin[64 + mg*2 + 1][b] = tanhf_(a1);
  }

  for (int cs = 0; cs < 2; ++cs){
    const float* cw    = cs ? c2w : c1w;
    const float* cbias = cs ? c2b : c1b;
    const float* lb    = cs ? l2b : l1b;

    __syncthreads();
    {
      const int e = tid & 63, rr = tid >> 6;
      #pragma unroll
      for (int t = 0; t < 5; ++t)
        #pragma unroll
        for (int i = 0; i < 2; ++i){
          const int bb = rr*2 + i;
          sm[t][e][bb] = bf2f(Mbf[((size_t)(21 + cs*5 + t)*BN + b0 + bb)*64 + e]);
        }
      for (int r2 = tid; r2 < 1536; r2 += 256){
        const int o = r2 >> 7, j = r2 & 127;
        cwS[o][j] = cw[o*128 + j];
      }
    }
    __syncthreads();

    if (mg < 24){
      const int o = mg >> 1, hb = (mg & 1) * 2;
      float a0 = cbias[o], a1 = cbias[o];
      #pragma unroll 4
      for (int e = 0; e < 64; ++e){
        float w0 = cwS[o][e], w1 = cwS[o][64 + e];
        float s0 = sm[hb][e][b], s1 = sm[hb+1][e][b], s2 = sm[hb+2][e][b];
        a0 += w0*s0 + w1*s1;
        a1 += w0*s1 + w1*s2;
      }
      co[o*4 + hb][b]     = fmaxf(a0, 0.f);
      co[o*4 + hb + 1][b] = fmaxf(a1, 0.f);
    }
    __syncthreads();

    {
      float a0 = lb[mg*2], a1 = lb[mg*2+1];
      #pragma unroll
      for (int k = 0; k < 24; ++k){
        const int p = k >= 12, o = k - (p ? 12 : 0);
        float f = fmaxf(co[o*4 + 2*p][b], co[o*4 + 2*p + 1][b]);
        float2 lv = *(const float2*)(lwT + (cs*24 + k)*64 + mg*2);
        a0 += lv.x * f; a1 += lv.y * f;
      }
      cb[320 + cs*64 + mg*2][b]     = fmaxf(a0, 0.f);
      cb[320 + cs*64 + mg*2 + 1][b] = fmaxf(a1, 0.f);
    }
  }

  __syncthreads();
  {
    float a0 = cqb[mg*2], a1 = cqb[mg*2+1];
    #pragma unroll 8
    for (int k = 0; k < 448; ++k){
      float a = cb[k][b];
      float2 wv = *(const float2*)(cqwT + k*64 + mg*2);
      a0 += wv.x * a; a1 += wv.y * a;
    }
    qwin[mg*2][b]     = tanhf_(a0);
    qwin[mg*2 + 1][b] = tanhf_(a1);
  }
  __syncthreads();
  {
    float a0 = cqub[mg*2], a1 = cqub[mg*2+1];
    #pragma unroll 8
    for (int k = 0; k < 128; ++k){
      float a = qwin[k][b];
      float2 wv = *(const float2*)(cquwT + k*64 + mg*2);
      a0 += wv.x * a; a1 += wv.y * a;
    }
    float2 dv = *(const float2*)(dww + mg*2);
    red[mg][b] = dv.x * tanhf_(a0) + dv.y * tanhf_(a1);
  }
  __syncthreads();
  if (tid < 8){
    float s = dwb[0];
    #pragma unroll 8
    for (int g = 0; g < 32; ++g) s += red[g][tid];
    out[b0 + tid] = s;
  }
}

extern "C" void kernel_launch(void* const* d_in, const int* in_sizes, int n_in,
                              void* d_out, int out_size, void* d_ws, size_t ws_size,
                              hipStream_t stream) {
  const float* x    = (const float*)d_in[0];
  const float* we   = (const float*)d_in[1];
  const float* Wih  = (const float*)d_in[2];
  const float* Whh  = (const float*)d_in[3];
  const float* bihp = (const float*)d_in[4];
  const float* bhhp = (const float*)d_in[5];
  const float* h0   = (const float*)d_in[6];
  const float* c0   = (const float*)d_in[7];
  const float* wl   = (const float*)d_in[8];
  const float* bl   = (const float*)d_in[9];
  const float* c1w  = (const float*)d_in[10];
  const float* c1b  = (const float*)d_in[11];
  const float* l1w  = (const float*)d_in[12];
  const float* l1b  = (const float*)d_in[13];
  const float* c2w  = (const float*)d_in[14];
  const float* c2b  = (const float*)d_in[15];
  const float* l2w  = (const float*)d_in[16];
  const float* l2b  = (const float*)d_in[17];
  const float* ww   = (const float*)d_in[18];
  const float* wb   = (const float*)d_in[19];
  const float* cqw  = (const float*)d_in[20];
  const float* cqb  = (const float*)d_in[21];
  const float* cquw = (const float*)d_in[22];
  const float* cqub = (const float*)d_in[23];
  const float* dww  = (const float*)d_in[24];
  const float* dwb  = (const float*)d_in[25];

  char* ws = (char*)d_ws;
  int*   cnt8  = (int*)ws;                      // 992 B (pad 1024)
  u16*   Mbf   = (u16*)(ws + 1024);             // 16,252,928
  u16*   Wcb   = (u16*)(ws + 16253952);         // 262,144
  u16*   wlb   = (u16*)(ws + 16516096);         // 32,768
  float* bias  = (float*)(ws + 16548864);       // 4,096
  float* S     = (float*)(ws + 16552960);       // 4,194,304
  float* cqwT  = (float*)(ws + 20747264);       // 114,688
  float* cquwT = (float*)(ws + 20861952);       // 32,768
  float* wwT   = (float*)(ws + 20894720);       // 20,736
  float* lwT   = (float*)(ws + 20915456);       // 12,288

  count_kernel<<<248, 256, 0, stream>>>(x, cnt8);
  meansprep_kernel<<<2741, 256, 0, stream>>>(x, we, cnt8, Mbf,
      Wih, Whh, wl, bihp, bhhp, cqw, cquw, ww, l1w, l2w,
      Wcb, wlb, bias, cqwT, cquwT, wwT, lwT);
  lstm_kernel<<<256, 256, 0, stream>>>(Wcb, wlb, bias, Mbf, h0, c0, bl, S);
  final_kernel<<<512, 256, 0, stream>>>(x, Mbf, S,
      c1w, c1b, c2w, c2b, l1b, l2b,
      wwT, wb, cqwT, cqb, cquwT, cqub, lwT, dww, dwb, (float*)d_out);
}

// Round 7
// 343.421 us; speedup vs baseline: 1.0468x; 1.0134x over previous
//
#include <hip/hip_runtime.h>
#include <math.h>

#define BN 4096
typedef unsigned short u16;
typedef unsigned int   u32;
typedef short bfx8 __attribute__((ext_vector_type(8)));
typedef float fx4  __attribute__((ext_vector_type(4)));

// ---- chunk tables: (base row in x, rows used) for the 31 masked means ----
__device__ const int c_base[31] = {
  276,
  211, 224, 237, 250, 263,
  662, 672, 682, 692, 702,
  612, 622, 632, 642, 652,
  397, 410, 423, 436, 449,
  512, 522, 532, 542, 552,
  862, 872, 882, 892, 902
};
__device__ const int c_rows[31] = {
  10,
  10,10,10,10,10,
  5,5,5,5,5,
  5,5,5,5,5,
  10,10,10,10,10,
  5,5,5,5,5,
  5,5,5,5,5
};

__device__ __forceinline__ u16 f2bf(float f){
  u32 u = __float_as_uint(f);
  return (u16)((u + 0x7FFFu + ((u >> 16) & 1u)) >> 16);   // RNE
}
__device__ __forceinline__ float bf2f(u16 h){ return __uint_as_float(((u32)h) << 16); }
__device__ __forceinline__ float4 ld4(const float* p){ return *(const float4*)p; }
__device__ __forceinline__ float frcp(float x){ return __builtin_amdgcn_rcpf(x); }
__device__ __forceinline__ float sigf(float v){ return frcp(1.f + __expf(-v)); }
__device__ __forceinline__ float tanhf_(float v){ return 1.f - 2.f*frcp(1.f + __expf(2.f*v)); }

// ---- Kernel 1: sign-count partials. Block (c,part) writes its own slot. ----
extern "C" __global__ __launch_bounds__(256)
void count_kernel(const float* __restrict__ x, int* __restrict__ cnt8){
  __shared__ int red[256];
  const int c = blockIdx.x >> 3, part = blockIdx.x & 7;
  const int base = c_base[c], rows = c_rows[c];
  const int n_per = rows * 512;
  const int start = part * n_per;
  int s = 0;
  for (int i = start + threadIdx.x; i < start + n_per; i += 256){
    float v = x[(size_t)(base + (i >> 12)) * BN + (i & 4095)];
    s += (v > 0.f) ? 1 : ((v < 0.f) ? -1 : 0);
  }
  red[threadIdx.x] = s; __syncthreads();
  for (int off = 128; off > 0; off >>= 1){
    if (threadIdx.x < off) red[threadIdx.x] += red[threadIdx.x + off];
    __syncthreads();
  }
  if (threadIdx.x == 0) cnt8[blockIdx.x] = red[0];
}

// ---- Kernel 2: means (blocks 0..1983) + weight prep (rest) ----
// Vectorized gather: lane = (jsub = lane>>4, d4 = lane&15). Each lane loads a
// float4 (16B) of its row -> one dwordx4 instruction covers 4 batches x 4 lines
// = 16 lines in flight per tracked VMEM op (4x the depth of scalar gathers).
// Per-element summation order identical to the scalar version (bit-exact).
template<int ROWS>
__device__ __forceinline__ void means_body16v(const float* __restrict__ x,
                                              const float* __restrict__ we,
                                              float L, int base, int b0,
                                              int jsub, int d4, fx4* acc){
  #pragma unroll
  for (int jg = 0; jg < 4; ++jg){ acc[jg].x=0.f; acc[jg].y=0.f; acc[jg].z=0.f; acc[jg].w=0.f; }
  #pragma unroll
  for (int r = 0; r < ROWS; ++r){
    const float* xrow = x + (size_t)(base + r) * BN + b0;
    float wr = ((float)r < L) ? 1.f : 0.f;
    #pragma unroll
    for (int jg = 0; jg < 4; ++jg){
      int idx = (int)xrow[jg*4 + jsub];          // broadcast within 16-lane group
      fx4 v = *(const fx4*)(we + (size_t)idx * 64 + d4*4);
      acc[jg].x += wr * v.x;
      acc[jg].y += wr * v.y;
      acc[jg].z += wr * v.z;
      acc[jg].w += wr * v.w;
    }
  }
}

extern "C" __global__ __launch_bounds__(256)
void meansprep_kernel(const float* __restrict__ x, const float* __restrict__ we,
                      const int* __restrict__ cnt8, u16* __restrict__ Mbf,
                      const float* __restrict__ Wih, const float* __restrict__ Whh,
                      const float* __restrict__ wl,  const float* __restrict__ bih,
                      const float* __restrict__ bhh,
                      const float* __restrict__ cqw, const float* __restrict__ cquw,
                      const float* __restrict__ ww,  const float* __restrict__ l1w,
                      const float* __restrict__ l2w,
                      u16* __restrict__ Wcb, u16* __restrict__ wlb,
                      float* __restrict__ bias_sum,
                      float* __restrict__ cqwT, float* __restrict__ cquwT,
                      float* __restrict__ wwT,  float* __restrict__ lwT){
  const int blk = blockIdx.x;
  if (blk < 1984){
    const int c = blk >> 6, tile = blk & 63;
    const int w = threadIdx.x >> 6, lane = threadIdx.x & 63;
    const int jsub = lane >> 4, d4 = lane & 15;
    const int b0 = tile * 64 + w * 16;
    const int base = c_base[c], rows = c_rows[c];
    int n = 0;
    #pragma unroll
    for (int p = 0; p < 8; ++p) n += cnt8[c*8 + p];
    const float L = fminf(fmaxf((float)n, 1.f), (float)rows);
    fx4 acc[4];
    if (rows == 5) means_body16v<5>(x, we, L, base, b0, jsub, d4, acc);
    else          means_body16v<10>(x, we, L, base, b0, jsub, d4, acc);
    const float rL = 1.f / L;
    #pragma unroll
    for (int jg = 0; jg < 4; ++jg){
      const int j = jg*4 + jsub;
      float m0 = acc[jg].x * rL, m1 = acc[jg].y * rL;
      float m2 = acc[jg].z * rL, m3 = acc[jg].w * rL;
      u32* dst = (u32*)(Mbf + ((size_t)c * BN + b0 + j) * 64 + d4*4);
      dst[0] = (u32)f2bf(m0) | ((u32)f2bf(m1) << 16);
      dst[1] = (u32)f2bf(m2) | ((u32)f2bf(m3) << 16);
    }
    return;
  }
  int idx = (blk - 1984) * 256 + threadIdx.x;
  if (idx < 131072){
    int s = idx >> 15, rem = idx & 32767, n = rem >> 7, k = rem & 127;
    float v = (k < 64) ? Wih[s*16384 + n*64 + k] : Whh[s*16384 + n*64 + (k-64)];
    Wcb[idx] = f2bf(v);
  } else if (idx < 147456){
    int j = idx - 131072;
    wlb[j] = f2bf(wl[j]);
  } else if (idx < 148480){
    int j = idx - 147456;
    bias_sum[j] = bih[j] + bhh[j];
  } else if (idx < 177152){
    int j = idx - 148480;                    // cqwT[448][64]
    int k = j >> 6, m = j & 63;
    cqwT[j] = cqw[m*448 + k];
  } else if (idx < 185344){
    int j = idx - 177152;                    // cquwT[128][64]
    int k = j >> 6, m = j & 63;
    cquwT[j] = cquw[m*128 + k];
  } else if (idx < 190528){
    int j = idx - 185344;                    // wwT[81][64]
    int k = j >> 6, m = j & 63;
    wwT[j] = ww[m*81 + k];
  } else if (idx < 193600){
    int j = idx - 190528;                    // lwT[2][24][64]
    int cs = j >= 1536;
    int r = j - (cs ? 1536 : 0);
    int k = r >> 6, m = r & 63;
    lwT[j] = (cs ? l2w : l1w)[m*24 + k];
  }
}

// ---- Kernel 3: LSTM streams via bf16 MFMA ----
extern "C" __global__ __launch_bounds__(256, 1)
void lstm_kernel(const u16* __restrict__ Wcb, const u16* __restrict__ wlb,
                 const float* __restrict__ bias_sum, const u16* __restrict__ Mbf,
                 const float* __restrict__ h0, const float* __restrict__ c0,
                 const float* __restrict__ bl, float* __restrict__ S){
  __shared__ u16 Xh[64][136];

  const int tid = threadIdx.x, w = tid >> 6, lane = tid & 63;
  const int quad = lane >> 4, l0 = lane & 15;
  const int st = blockIdx.x & 3, tile = blockIdx.x >> 2, b0 = tile * 64;
  const int brow = 16 * w + l0;
  const u16* Wc = Wcb + (size_t)st * 32768;

  fx4 bias4[16];
  #pragma unroll
  for (int mt = 0; mt < 16; ++mt)
    bias4[mt] = *(const fx4*)(bias_sum + st*256 + mt*16 + quad*4);

  float cst[4][4];
  #pragma unroll
  for (int dc = 0; dc < 4; ++dc){
    float4 v = ld4(c0 + ((size_t)st*BN + b0 + brow)*64 + dc*16 + quad*4);
    cst[dc][0]=v.x; cst[dc][1]=v.y; cst[dc][2]=v.z; cst[dc][3]=v.w;
  }
  {
    const float* hp = h0 + ((size_t)st*BN + b0 + brow)*64 + quad*16;
    #pragma unroll
    for (int i = 0; i < 4; ++i){
      float4 v = ld4(hp + i*4);
      u32* dst = (u32*)&Xh[brow][64 + quad*16 + i*4];
      dst[0] = (u32)f2bf(v.x) | ((u32)f2bf(v.y) << 16);
      dst[1] = (u32)f2bf(v.z) | ((u32)f2bf(v.w) << 16);
    }
  }

  for (int t = 0; t < 5; ++t){
    {
      const u16* src = Mbf + ((size_t)(1 + st*5 + t)*BN + b0 + brow)*64 + quad*16;
      *(uint4*)&Xh[brow][quad*16]     = *(const uint4*)src;
      *(uint4*)&Xh[brow][quad*16 + 8] = *(const uint4*)(src + 8);
    }
    __syncthreads();

    fx4 acc[16];
    #pragma unroll
    for (int mt = 0; mt < 16; ++mt) acc[mt] = bias4[mt];
    #pragma unroll
    for (int kc = 0; kc < 4; ++kc){
      bfx8 bfr = *(const bfx8*)&Xh[brow][kc*32 + quad*8];
      #pragma unroll
      for (int mt = 0; mt < 16; ++mt){
        bfx8 afr = *(const bfx8*)(Wc + (size_t)(mt*16 + l0)*128 + kc*32 + quad*8);
        acc[mt] = __builtin_amdgcn_mfma_f32_16x16x32_bf16(afr, bfr, acc[mt], 0, 0, 0);
      }
    }
    #pragma unroll
    for (int dc = 0; dc < 4; ++dc){
      u16 hv[4];
      #pragma unroll
      for (int r = 0; r < 4; ++r){
        float ig = sigf(acc[dc][r]);
        float fg = sigf(acc[4 + dc][r]);
        float gg = tanhf_(acc[8 + dc][r]);
        float og = sigf(acc[12 + dc][r]);
        float cc = fg * cst[dc][r] + ig * gg;
        cst[dc][r] = cc;
        hv[r] = f2bf(og * tanhf_(cc));
      }
      u32* dst = (u32*)&Xh[brow][64 + dc*16 + quad*4];
      dst[0] = (u32)hv[0] | ((u32)hv[1] << 16);
      dst[1] = (u32)hv[2] | ((u32)hv[3] << 16);
    }
    __syncthreads();
  }

  fx4 acc2[4];
  #pragma unroll
  for (int mt = 0; mt < 4; ++mt){ acc2[mt].x=0.f; acc2[mt].y=0.f; acc2[mt].z=0.f; acc2[mt].w=0.f; }
  #pragma unroll
  for (int kc = 0; kc < 2; ++kc){
    bfx8 bfr = *(const bfx8*)&Xh[brow][64 + kc*32 + quad*8];
    #pragma unroll
    for (int mt = 0; mt < 4; ++mt){
      bfx8 afr = *(const bfx8*)(wlb + (size_t)st*4096 + (size_t)(mt*16 + l0)*64 + kc*32 + quad*8);
      acc2[mt] = __builtin_amdgcn_mfma_f32_16x16x32_bf16(afr, bfr, acc2[mt], 0, 0, 0);
    }
  }
  #pragma unroll
  for (int mt = 0; mt < 4; ++mt){
    fx4 blv = *(const fx4*)(bl + st*64 + mt*16 + quad*4);
    fx4 o;
    o.x = tanhf_(acc2[mt].x + blv.x);
    o.y = tanhf_(acc2[mt].y + blv.y);
    o.z = tanhf_(acc2[mt].z + blv.z);
    o.w = tanhf_(acc2[mt].w + blv.w);
    *(fx4*)(S + ((size_t)st*BN + b0 + brow)*64 + mt*16 + quad*4) = o;
  }
}

// ---- Kernel 4: tail. Block = 8 batch, thread = (b = tid&7, mg = tid>>3). ----
extern "C" __global__ __launch_bounds__(256)
void final_kernel(
    const float* __restrict__ x,   const u16* __restrict__ Mbf,
    const float* __restrict__ S,
    const float* __restrict__ c1w, const float* __restrict__ c1b,
    const float* __restrict__ c2w, const float* __restrict__ c2b,
    const float* __restrict__ l1b, const float* __restrict__ l2b,
    const float* __restrict__ wwT, const float* __restrict__ wb,
    const float* __restrict__ cqwT,const float* __restrict__ cqb,
    const float* __restrict__ cquwT,const float* __restrict__ cqub,
    const float* __restrict__ lwT, const float* __restrict__ dww,
    const float* __restrict__ dwb, float* __restrict__ out)
{
  __shared__ float cb[448][9];
  __shared__ float qwin[128][9];
  __shared__ float sm[5][64][9];
  __shared__ float co[48][9];
  __shared__ float cwS[12][130];
  __shared__ float red[32][8];

  const int tid = threadIdx.x;
  const int b   = tid & 7;
  const int mg  = tid >> 3;
  const int b0  = blockIdx.x * 8;

  {
    const int e = tid & 63, rr = tid >> 6;
    #pragma unroll
    for (int i = 0; i < 2; ++i){
      const int bb = rr*2 + i;
      cb[e][bb] = bf2f(Mbf[(size_t)(b0 + bb)*64 + e]);
      #pragma unroll
      for (int s = 0; s < 4; ++s)
        cb[64 + s*64 + e][bb] = S[((size_t)s*BN + b0 + bb)*64 + e];
    }
  }

  {
    float a0 = wb[mg*2], a1 = wb[mg*2+1];
    #pragma unroll 4
    for (int k = 0; k < 81; ++k){
      float xv = x[(size_t)k*BN + b0 + b];
      float2 wv = *(const float2*)(wwT + k*64 + mg*2);
      a0 += wv.x * xv; a1 += wv.y * xv;
    }
    qwin[64 + mg*2][b]     = tanhf_(a0);
    qwin[64 + mg*2 + 1][b] = tanhf_(a1);
  }

  for (int cs = 0; cs < 2; ++cs){
    const float* cw    = cs ? c2w : c1w;
    const float* cbias = cs ? c2b : c1b;
    const float* lb    = cs ? l2b : l1b;

    __syncthreads();
    {
      const int e = tid & 63, rr = tid >> 6;
      #pragma unroll
      for (int t = 0; t < 5; ++t)
        #pragma unroll
        for (int i = 0; i < 2; ++i){
          const int bb = rr*2 + i;
          sm[t][e][bb] = bf2f(Mbf[((size_t)(21 + cs*5 + t)*BN + b0 + bb)*64 + e]);
        }
      for (int r2 = tid; r2 < 1536; r2 += 256){
        const int o = r2 >> 7, j = r2 & 127;
        cwS[o][j] = cw[o*128 + j];
      }
    }
    __syncthreads();

    if (mg < 24){
      const int o = mg >> 1, hb = (mg & 1) * 2;
      float a0 = cbias[o], a1 = cbias[o];
      #pragma unroll 4
      for (int e = 0; e < 64; ++e){
        float w0 = cwS[o][e], w1 = cwS[o][64 + e];
        float s0 = sm[hb][e][b], s1 = sm[hb+1][e][b], s2 = sm[hb+2][e][b];
        a0 += w0*s0 + w1*s1;
        a1 += w0*s1 + w1*s2;
      }
      co[o*4 + hb][b]     = fmaxf(a0, 0.f);
      co[o*4 + hb + 1][b] = fmaxf(a1, 0.f);
    }
    __syncthreads();

    {
      float a0 = lb[mg*2], a1 = lb[mg*2+1];
      #pragma unroll
      for (int k = 0; k < 24; ++k){
        const int p = k >= 12, o = k - (p ? 12 : 0);
        float f = fmaxf(co[o*4 + 2*p][b], co[o*4 + 2*p + 1][b]);
        float2 lv = *(const float2*)(lwT + (cs*24 + k)*64 + mg*2);
        a0 += lv.x * f; a1 += lv.y * f;
      }
      cb[320 + cs*64 + mg*2][b]     = fmaxf(a0, 0.f);
      cb[320 + cs*64 + mg*2 + 1][b] = fmaxf(a1, 0.f);
    }
  }

  __syncthreads();
  {
    float a0 = cqb[mg*2], a1 = cqb[mg*2+1];
    #pragma unroll 8
    for (int k = 0; k < 448; ++k){
      float a = cb[k][b];
      float2 wv = *(const float2*)(cqwT + k*64 + mg*2);
      a0 += wv.x * a; a1 += wv.y * a;
    }
    qwin[mg*2][b]     = tanhf_(a0);
    qwin[mg*2 + 1][b] = tanhf_(a1);
  }
  __syncthreads();
  {
    float a0 = cqub[mg*2], a1 = cqub[mg*2+1];
    #pragma unroll 8
    for (int k = 0; k < 128; ++k){
      float a = qwin[k][b];
      float2 wv = *(const float2*)(cquwT + k*64 + mg*2);
      a0 += wv.x * a; a1 += wv.y * a;
    }
    float2 dv = *(const float2*)(dww + mg*2);
    red[mg][b] = dv.x * tanhf_(a0) + dv.y * tanhf_(a1);
  }
  __syncthreads();
  if (tid < 8){
    float s = dwb[0];
    #pragma unroll 8
    for (int g = 0; g < 32; ++g) s += red[g][tid];
    out[b0 + tid] = s;
  }
}

extern "C" void kernel_launch(void* const* d_in, const int* in_sizes, int n_in,
                              void* d_out, int out_size, void* d_ws, size_t ws_size,
                              hipStream_t stream) {
  const float* x    = (const float*)d_in[0];
  const float* we   = (const float*)d_in[1];
  const float* Wih  = (const float*)d_in[2];
  const float* Whh  = (const float*)d_in[3];
  const float* bihp = (const float*)d_in[4];
  const float* bhhp = (const float*)d_in[5];
  const float* h0   = (const float*)d_in[6];
  const float* c0   = (const float*)d_in[7];
  const float* wl   = (const float*)d_in[8];
  const float* bl   = (const float*)d_in[9];
  const float* c1w  = (const float*)d_in[10];
  const float* c1b  = (const float*)d_in[11];
  const float* l1w  = (const float*)d_in[12];
  const float* l1b  = (const float*)d_in[13];
  const float* c2w  = (const float*)d_in[14];
  const float* c2b  = (const float*)d_in[15];
  const float* l2w  = (const float*)d_in[16];
  const float* l2b  = (const float*)d_in[17];
  const float* ww   = (const float*)d_in[18];
  const float* wb   = (const float*)d_in[19];
  const float* cqw  = (const float*)d_in[20];
  const float* cqb  = (const float*)d_in[21];
  const float* cquw = (const float*)d_in[22];
  const float* cqub = (const float*)d_in[23];
  const float* dww  = (const float*)d_in[24];
  const float* dwb  = (const float*)d_in[25];

  char* ws = (char*)d_ws;
  int*   cnt8  = (int*)ws;                      // 992 B (pad 1024)
  u16*   Mbf   = (u16*)(ws + 1024);             // 16,252,928
  u16*   Wcb   = (u16*)(ws + 16253952);         // 262,144
  u16*   wlb   = (u16*)(ws + 16516096);         // 32,768
  float* bias  = (float*)(ws + 16548864);       // 4,096
  float* S     = (float*)(ws + 16552960);       // 4,194,304
  float* cqwT  = (float*)(ws + 20747264);       // 114,688
  float* cquwT = (float*)(ws + 20861952);       // 32,768
  float* wwT   = (float*)(ws + 20894720);       // 20,736
  float* lwT   = (float*)(ws + 20915456);       // 12,288

  count_kernel<<<248, 256, 0, stream>>>(x, cnt8);
  meansprep_kernel<<<2741, 256, 0, stream>>>(x, we, cnt8, Mbf,
      Wih, Whh, wl, bihp, bhhp, cqw, cquw, ww, l1w, l2w,
      Wcb, wlb, bias, cqwT, cquwT, wwT, lwT);
  lstm_kernel<<<256, 256, 0, stream>>>(Wcb, wlb, bias, Mbf, h0, c0, bl, S);
  final_kernel<<<512, 256, 0, stream>>>(x, Mbf, S,
      c1w, c1b, c2w, c2b, l1b, l2b,
      wwT, wb, cqwT, cqb, cquwT, cqub, lwT, dww, dwb, (float*)d_out);
}